// Round 1
// baseline (333.685 us; speedup 1.0000x reference)
//
#include <hip/hip_runtime.h>
#include <math.h>

#define FIN  512
#define HDIM 128
#define CDIM 40
#define CPAD 48
#define CAP  64   // max in-degree capacity; Poisson(16) => P(deg>=64) ~ 1e-19/node

typedef __attribute__((ext_vector_type(8))) short shortx8;   // 8 bf16 = 4 VGPRs
typedef __attribute__((ext_vector_type(4))) float f32x4;     // MFMA accumulator
typedef __attribute__((ext_vector_type(2))) float floatx2;

__device__ inline unsigned short f2bf(float x) {             // fp32 -> bf16 (RNE)
    unsigned u = __builtin_bit_cast(unsigned, x);
    unsigned r = u + 0x7fffu + ((u >> 16) & 1u);
    return (unsigned short)(r >> 16);
}
__device__ inline float bfu(unsigned short v) { return __builtin_bit_cast(float, (unsigned)v << 16); }
// packed bucket entry: src<<15 | (bits(w)+0x8000)>>16 (15 bits; w in (0,1) => sign=0)
__device__ inline float wdec(unsigned p) { return __builtin_bit_cast(float, (p & 0x7fffu) << 16); }
// fp8 e4m3 (OCP) encode/decode via gfx950 HW converts
__device__ inline unsigned char f2fp8(float x) {
    return (unsigned char)(__builtin_amdgcn_cvt_pk_fp8_f32(x, x, 0, false) & 0xff);
}
__device__ inline floatx2 fp8x2_dec(unsigned short v) {
    return __builtin_amdgcn_cvt_pk_f32_fp8((int)(unsigned)v, false);
}

// ---------- fill buckets + degree sum in ONE packed 64-bit atomic ----------
// cursor[c] += (1<<40) | round(w * 2^32);  old>>40 = slot, low 40 bits accumulate sum(w)
// Blocks >= eblocks do the (independent) weight transpose/cast instead.
#define PREPB 280   // (FIN*HDIM + CPAD*HDIM)/256 = 71680/256
__global__ void k_fill(const int* __restrict__ row, const int* __restrict__ col,
                       const float* __restrict__ w,
                       unsigned long long* __restrict__ cursor,
                       unsigned* __restrict__ bkt, int E, int eblocks,
                       const float* __restrict__ W1, const float* __restrict__ W2,
                       unsigned short* __restrict__ W1T, unsigned short* __restrict__ W2T) {
    if ((int)blockIdx.x >= eblocks) {
        const int i = ((int)blockIdx.x - eblocks) * 256 + (int)threadIdx.x;
        if (i < FIN * HDIM) {
            const int k = i >> 7, nn = i & 127;
            W1T[nn * FIN + k] = f2bf(W1[i]);
        } else {
            const int j = i - FIN * HDIM;
            const int nn = j >> 7, k = j & 127;
            W2T[j] = (nn < CDIM) ? f2bf(W2[k * CDIM + nn]) : (unsigned short)0;
        }
        return;
    }
    const int e = blockIdx.x * blockDim.x + threadIdx.x;
    if (e >= E) return;
    const int c = col[e];
    const float we = w[e];
    const unsigned long long wfix = (unsigned long long)(we * 4294967296.0f); // w<1 => <2^32
    const unsigned long long old = atomicAdd(&cursor[c], (1ULL << 40) | wfix);
    const int p = (int)(old >> 40);
    const unsigned wb = (__builtin_bit_cast(unsigned, we) + 0x8000u) >> 16;   // round, 7-bit mant
    if (p < CAP) bkt[(size_t)c * CAP + p] = ((unsigned)row[e] << 15) | (wb & 0x7fffu);
}

// ---------- degree unpack only (weight prep moved into k_fill) ----------
__global__ void k_prep(const unsigned long long* __restrict__ cursor,
                       int* __restrict__ cnt, float* __restrict__ dinv, int n) {
    const int i = blockIdx.x * 256 + threadIdx.x;
    if (i < n) {
        const unsigned long long p = cursor[i];
        cnt[i] = min((int)(p >> 40), CAP);
        const float wsum = (float)(p & ((1ULL << 40) - 1)) * 2.3283064365386963e-10f;
        dinv[i] = rsqrtf(1.0f + wsum);
    }
}

// ---------- GEMM1 (MFMA): h1f8[M,128] (fp8 e4m3) = dinv[m] * (bf16(A) @ W1T^T) ----------
// 64-row blocks (782 total): ~3-5 resident blocks/CU instead of 1.5 at 128-row tiles.
#define G1_LDA 72   // 64 + 8 pad
__global__ __launch_bounds__(256) void k_gemm1(const float* __restrict__ A,
                                               const unsigned short* __restrict__ W1T,
                                               const float* __restrict__ dinv,
                                               unsigned char* __restrict__ h1f8, int M) {
    __shared__ short As[64 * G1_LDA];
    __shared__ short Bs[128 * G1_LDA];
    const int tid  = threadIdx.x;
    const int wave = tid >> 6;
    const int lane = tid & 63;
    const int quad = lane >> 4;
    const int mr   = lane & 15;
    const int n0w  = wave * 32;            // each wave: all 64 m-rows x 32 n-cols
    const int m0b  = blockIdx.x * 64;

    const int srowA = tid >> 2, spartA = tid & 3;   // A: 64 rows x 4 parts (16 floats)
    const int srowB = tid >> 1, spartB = tid & 1;   // B: 128 rows x 2 parts (32 shorts)

    f32x4 acc[4][2];
#pragma unroll
    for (int i = 0; i < 4; i++)
#pragma unroll
        for (int j = 0; j < 2; j++) acc[i][j] = (f32x4)0.f;

    const int growA = m0b + srowA;
    const bool okA = growA < M;
    const float* ap = A + (size_t)growA * FIN + spartA * 16;
    const unsigned short* bp = W1T + (size_t)srowB * FIN + spartB * 32;

    for (int k0 = 0; k0 < FIN; k0 += 64) {
#pragma unroll
        for (int i = 0; i < 2; i++) {
            float4 v0 = make_float4(0.f, 0.f, 0.f, 0.f), v1 = v0;
            if (okA) {
                v0 = *(const float4*)(ap + k0 + i * 8);
                v1 = *(const float4*)(ap + k0 + i * 8 + 4);
            }
            shortx8 pk;
            pk[0] = (short)f2bf(v0.x); pk[1] = (short)f2bf(v0.y);
            pk[2] = (short)f2bf(v0.z); pk[3] = (short)f2bf(v0.w);
            pk[4] = (short)f2bf(v1.x); pk[5] = (short)f2bf(v1.y);
            pk[6] = (short)f2bf(v1.z); pk[7] = (short)f2bf(v1.w);
            *(shortx8*)&As[srowA * G1_LDA + spartA * 16 + i * 8] = pk;
        }
#pragma unroll
        for (int i = 0; i < 4; i++)
            *(shortx8*)&Bs[srowB * G1_LDA + spartB * 32 + i * 8] =
                *(const shortx8*)(bp + k0 + i * 8);
        __syncthreads();

#pragma unroll
        for (int kk = 0; kk < 2; kk++) {
            shortx8 af[4], bfr[2];
#pragma unroll
            for (int mt = 0; mt < 4; mt++)
                af[mt] = *(shortx8*)&As[(mt * 16 + mr) * G1_LDA + kk * 32 + quad * 8];
#pragma unroll
            for (int nt = 0; nt < 2; nt++)
                bfr[nt] = *(shortx8*)&Bs[(n0w + nt * 16 + mr) * G1_LDA + kk * 32 + quad * 8];
#pragma unroll
            for (int mt = 0; mt < 4; mt++)
#pragma unroll
                for (int nt = 0; nt < 2; nt++)
                    acc[mt][nt] = __builtin_amdgcn_mfma_f32_16x16x32_bf16(
                        af[mt], bfr[nt], acc[mt][nt], 0, 0, 0);
        }
        __syncthreads();
    }
#pragma unroll
    for (int mt = 0; mt < 4; mt++)
#pragma unroll
        for (int r = 0; r < 4; r++) {
            const int om = m0b + mt * 16 + quad * 4 + r;
            if (om < M) {
                const float dv = dinv[om];
#pragma unroll
                for (int nt = 0; nt < 2; nt++)
                    h1f8[(size_t)om * HDIM + n0w + nt * 16 + mr] = f2fp8(dv * acc[mt][nt][r]);
            }
        }
}

// ---------- FUSED gather1 + GEMM2 ----------
// Block = 64 nodes, 4 waves. Each wave gathers 16 nodes' x1 rows
// (relu(dinv*(sum w*h1'[r] + h1'[self]) + b1)) straight into LDS as bf16,
// then runs its own 16x48 MFMA tile against L2-resident W2T. x1 never
// touches global memory (saves 25.6 MB round-trip + one launch).
#define G2_LDA 136   // 128 + 8 pad
__global__ __launch_bounds__(256) void k_g1g2(
    const int* __restrict__ cnt_arr, const unsigned* __restrict__ bkt,
    const unsigned char* __restrict__ h1f8,   // fp8 rows, 128 B pitch
    const float* __restrict__ dinv, const float* __restrict__ b1,
    const unsigned short* __restrict__ W2T,   // [CPAD][HDIM] bf16
    unsigned short* __restrict__ h2a, unsigned short* __restrict__ h2b,
    int n_nodes) {
    __shared__ short Xs[64 * G2_LDA];
    const int tid  = threadIdx.x;
    const int wave = tid >> 6;
    const int lane = tid & 63;
    const int loff = lane * 2;
    const int m0b  = blockIdx.x * 64;
    const float bias0 = b1[loff], bias1 = b1[loff + 1];

    for (int i = 0; i < 16; i++) {
        const int node = m0b + wave * 16 + i;
        unsigned val = 0u;
        if (node < n_nodes) {
            const int cnt = cnt_arr[node];
            const unsigned* base = bkt + (size_t)node * CAP;
            float a0 = 0.f, a1 = 0.f, c0 = 0.f, c1 = 0.f;
            int s = 0;
            for (; s + 8 <= cnt; s += 8) {
                const uint4 qa = *(const uint4*)(base + s);
                const uint4 qb = *(const uint4*)(base + s + 4);
                const unsigned short v0 = *(const unsigned short*)(h1f8 + (size_t)(qa.x >> 15) * HDIM + loff);
                const unsigned short v1 = *(const unsigned short*)(h1f8 + (size_t)(qa.y >> 15) * HDIM + loff);
                const unsigned short v2 = *(const unsigned short*)(h1f8 + (size_t)(qa.z >> 15) * HDIM + loff);
                const unsigned short v3 = *(const unsigned short*)(h1f8 + (size_t)(qa.w >> 15) * HDIM + loff);
                const unsigned short v4 = *(const unsigned short*)(h1f8 + (size_t)(qb.x >> 15) * HDIM + loff);
                const unsigned short v5 = *(const unsigned short*)(h1f8 + (size_t)(qb.y >> 15) * HDIM + loff);
                const unsigned short v6 = *(const unsigned short*)(h1f8 + (size_t)(qb.z >> 15) * HDIM + loff);
                const unsigned short v7 = *(const unsigned short*)(h1f8 + (size_t)(qb.w >> 15) * HDIM + loff);
                const floatx2 f0 = fp8x2_dec(v0), f1 = fp8x2_dec(v1), f2 = fp8x2_dec(v2), f3 = fp8x2_dec(v3);
                const floatx2 f4 = fp8x2_dec(v4), f5 = fp8x2_dec(v5), f6 = fp8x2_dec(v6), f7 = fp8x2_dec(v7);
                a0 += wdec(qa.x) * f0.x + wdec(qa.y) * f1.x + wdec(qa.z) * f2.x + wdec(qa.w) * f3.x;
                a1 += wdec(qa.x) * f0.y + wdec(qa.y) * f1.y + wdec(qa.z) * f2.y + wdec(qa.w) * f3.y;
                c0 += wdec(qb.x) * f4.x + wdec(qb.y) * f5.x + wdec(qb.z) * f6.x + wdec(qb.w) * f7.x;
                c1 += wdec(qb.x) * f4.y + wdec(qb.y) * f5.y + wdec(qb.z) * f6.y + wdec(qb.w) * f7.y;
            }
            for (; s + 4 <= cnt; s += 4) {
                const uint4 qa = *(const uint4*)(base + s);
                const unsigned short v0 = *(const unsigned short*)(h1f8 + (size_t)(qa.x >> 15) * HDIM + loff);
                const unsigned short v1 = *(const unsigned short*)(h1f8 + (size_t)(qa.y >> 15) * HDIM + loff);
                const unsigned short v2 = *(const unsigned short*)(h1f8 + (size_t)(qa.z >> 15) * HDIM + loff);
                const unsigned short v3 = *(const unsigned short*)(h1f8 + (size_t)(qa.w >> 15) * HDIM + loff);
                const floatx2 f0 = fp8x2_dec(v0), f1 = fp8x2_dec(v1), f2 = fp8x2_dec(v2), f3 = fp8x2_dec(v3);
                a0 += wdec(qa.x) * f0.x + wdec(qa.y) * f1.x + wdec(qa.z) * f2.x + wdec(qa.w) * f3.x;
                a1 += wdec(qa.x) * f0.y + wdec(qa.y) * f1.y + wdec(qa.z) * f2.y + wdec(qa.w) * f3.y;
            }
            for (; s < cnt; s++) {
                const unsigned p = base[s];
                const unsigned short v = *(const unsigned short*)(h1f8 + (size_t)(p >> 15) * HDIM + loff);
                const floatx2 f = fp8x2_dec(v);
                a0 += wdec(p) * f.x;
                a1 += wdec(p) * f.y;
            }
            a0 += c0; a1 += c1;
            const float dl = dinv[node];
            const unsigned short vs = *(const unsigned short*)(h1f8 + (size_t)node * HDIM + loff);
            const floatx2 fs = fp8x2_dec(vs);             // self-loop (h1' already dinv-scaled)
            a0 = fmaxf(dl * (a0 + fs.x) + bias0, 0.f);
            a1 = fmaxf(dl * (a1 + fs.y) + bias1, 0.f);
            val = (unsigned)f2bf(a0) | ((unsigned)f2bf(a1) << 16);
        }
        *(unsigned*)&Xs[(wave * 16 + i) * G2_LDA + loff] = val;
    }
    __syncthreads();

    // GEMM2: wave's 16 rows x 48 cols; B-fragments streamed from L2-resident W2T
    const int quad = lane >> 4;
    const int mr   = lane & 15;
    f32x4 acc[3];
#pragma unroll
    for (int nt = 0; nt < 3; nt++) acc[nt] = (f32x4)0.f;
#pragma unroll
    for (int kk = 0; kk < 4; kk++) {
        const shortx8 af = *(const shortx8*)&Xs[(wave * 16 + mr) * G2_LDA + kk * 32 + quad * 8];
#pragma unroll
        for (int nt = 0; nt < 3; nt++) {
            const shortx8 bfr = *(const shortx8*)(W2T + (size_t)(nt * 16 + mr) * HDIM + kk * 32 + quad * 8);
            acc[nt] = __builtin_amdgcn_mfma_f32_16x16x32_bf16(af, bfr, acc[nt], 0, 0, 0);
        }
    }
#pragma unroll
    for (int r = 0; r < 4; r++) {
        const int om = m0b + wave * 16 + quad * 4 + r;
        if (om < n_nodes) {
            const float dv = dinv[om];
#pragma unroll
            for (int nt = 0; nt < 2; nt++)    // cols 0..31 -> h2a (one 64B line/row)
                h2a[(size_t)om * 32 + nt * 16 + mr] = f2bf(dv * acc[nt][r]);
            if (mr < 8)                        // cols 32..39 -> h2b (L2-resident, 800KB)
                h2b[(size_t)om * 8 + mr] = f2bf(dv * acc[2][r]);
        }
    }
}

// ---------- gather layer2 + self-loop + bias + log_softmax, wave/node ----------
__global__ __launch_bounds__(256) void k_gather2(
    const int* __restrict__ cnt_arr, const unsigned* __restrict__ bkt,
    const unsigned short* __restrict__ h2a, const unsigned short* __restrict__ h2b,
    const float* __restrict__ dinv, const float* __restrict__ b2,
    float* __restrict__ out, int n_nodes) {
    const int node = blockIdx.x * 4 + (threadIdx.x >> 6);
    const int lane = threadIdx.x & 63;
    if (node >= n_nodes) return;
    const bool act = lane < CDIM;
    const int cnt = cnt_arr[node];
    const unsigned* base = bkt + (size_t)node * CAP;
    // lane -> {array, stride}: cols 0..31 from h2a (stride 32), 32..39 from h2b (stride 8)
    const unsigned short* hb = (lane < 32) ? (h2a + lane) : (h2b + (lane & 31 & 7));
    const int hstride = (lane < 32) ? 32 : 8;
    float acc = 0.f, accb = 0.f;
    int s = 0;
    for (; s + 4 <= cnt; s += 4) {
        const uint4 q = *(const uint4*)(base + s);
        if (act) {
            acc  += wdec(q.x) * bfu(hb[(size_t)(q.x >> 15) * hstride])
                  + wdec(q.y) * bfu(hb[(size_t)(q.y >> 15) * hstride]);
            accb += wdec(q.z) * bfu(hb[(size_t)(q.z >> 15) * hstride])
                  + wdec(q.w) * bfu(hb[(size_t)(q.w >> 15) * hstride]);
        }
    }
    for (; s < cnt; s++) {
        const unsigned p = base[s];
        if (act) acc += wdec(p) * bfu(hb[(size_t)(p >> 15) * hstride]);
    }
    acc += accb;
    if (act) {
        const float dl = dinv[node];
        acc = dl * (acc + bfu(hb[(size_t)node * hstride])) + b2[lane];
    }
    float m = act ? acc : -INFINITY;
#pragma unroll
    for (int off = 32; off; off >>= 1) m = fmaxf(m, __shfl_xor(m, off));
    float se = act ? expf(acc - m) : 0.f;
#pragma unroll
    for (int off = 32; off; off >>= 1) se += __shfl_xor(se, off);
    if (act) out[(size_t)node * CDIM + lane] = acc - m - logf(se);
}

extern "C" void kernel_launch(void* const* d_in, const int* in_sizes, int n_in,
                              void* d_out, int out_size, void* d_ws, size_t ws_size,
                              hipStream_t stream) {
    const float* features = (const float*)d_in[0];
    const int*   eidx     = (const int*)d_in[1];
    const float* ew       = (const float*)d_in[2];
    const float* W1       = (const float*)d_in[3];
    const float* b1       = (const float*)d_in[4];
    const float* W2       = (const float*)d_in[5];
    const float* b2       = (const float*)d_in[6];
    float* out = (float*)d_out;

    const int Nn = in_sizes[0] / FIN;   // 50000
    const int E  = in_sizes[2];         // 800000
    const int* row = eidx;
    const int* col = eidx + E;

    char* ws = (char*)d_ws;
    size_t off = 0;
    auto alloc = [&](size_t bytes) { void* p = ws + off; off += (bytes + 255) & ~(size_t)255; return p; };
    unsigned long long* cursor = (unsigned long long*)alloc((size_t)Nn * 8);
    int*      cnt          = (int*)     alloc((size_t)Nn * 4);
    float*    dinv         = (float*)   alloc((size_t)Nn * 4);
    unsigned* bkt          = (unsigned*)alloc((size_t)Nn * CAP * 4);
    unsigned short* W1T    = (unsigned short*)alloc((size_t)FIN * HDIM * 2);
    unsigned short* W2T    = (unsigned short*)alloc((size_t)CPAD * HDIM * 2);
    unsigned char*  h1f8   = (unsigned char*) alloc((size_t)Nn * HDIM);
    unsigned short* h2a    = (unsigned short*)alloc((size_t)Nn * 32 * 2);
    unsigned short* h2b    = (unsigned short*)alloc((size_t)Nn * 8 * 2);

    const int eblocks = (E + 255) / 256;

    // bucket build (packed 64-bit atomic per edge) + weight transpose in one launch
    hipMemsetAsync(cursor, 0, (size_t)Nn * 8, stream);
    k_fill<<<eblocks + PREPB, 256, 0, stream>>>(row, col, ew, cursor, bkt, E, eblocks,
                                                W1, W2, W1T, W2T);
    // degree unpack
    k_prep<<<(Nn + 255) / 256, 256, 0, stream>>>(cursor, cnt, dinv, Nn);
    // layer 1 transform
    k_gemm1<<<(Nn + 63) / 64, 256, 0, stream>>>(features, W1T, dinv, h1f8, Nn);
    // fused layer-1 aggregate + layer-2 transform (x1 stays in LDS)
    k_g1g2<<<(Nn + 63) / 64, 256, 0, stream>>>(cnt, bkt, h1f8, dinv, b1, W2T,
                                               h2a, h2b, Nn);
    // layer-2 aggregate + log_softmax
    k_gather2<<<(Nn + 3) / 4, 256, 0, stream>>>(cnt, bkt, h2a, h2b, dinv, b2, out, Nn);
}

// Round 2
// 313.936 us; speedup vs baseline: 1.0629x; 1.0629x over previous
//
#include <hip/hip_runtime.h>
#include <math.h>

#define FIN  512
#define HDIM 128
#define CDIM 40
#define CPAD 48
#define CAP  64   // max in-degree capacity; Poisson(16) => P(deg>=64) ~ 1e-19/node

typedef __attribute__((ext_vector_type(8))) short shortx8;   // 8 bf16 = 4 VGPRs
typedef __attribute__((ext_vector_type(4))) float f32x4;     // MFMA accumulator
typedef __attribute__((ext_vector_type(2))) float floatx2;

__device__ inline unsigned short f2bf(float x) {             // fp32 -> bf16 (RNE)
    unsigned u = __builtin_bit_cast(unsigned, x);
    unsigned r = u + 0x7fffu + ((u >> 16) & 1u);
    return (unsigned short)(r >> 16);
}
__device__ inline float bfu(unsigned short v) { return __builtin_bit_cast(float, (unsigned)v << 16); }
// packed bucket entry: src<<15 | (bits(w)+0x8000)>>16 (15 bits; w in (0,1) => sign=0)
__device__ inline float wdec(unsigned p) { return __builtin_bit_cast(float, (p & 0x7fffu) << 16); }
// fp8 e4m3 (OCP) encode/decode via gfx950 HW converts
__device__ inline unsigned char f2fp8(float x) {
    return (unsigned char)(__builtin_amdgcn_cvt_pk_fp8_f32(x, x, 0, false) & 0xff);
}
__device__ inline floatx2 fp8x2_dec(unsigned short v) {
    return __builtin_amdgcn_cvt_pk_f32_fp8((int)(unsigned)v, false);
}

// ---------- fill buckets + degree sum in ONE packed 64-bit atomic ----------
// cursor[c] += (1<<40) | round(w * 2^32);  old>>40 = slot, low 40 bits accumulate sum(w)
// Blocks >= eblocks do the (independent) weight transpose/cast instead.
#define PREPB 280   // (FIN*HDIM + CPAD*HDIM)/256 = 71680/256
__global__ void k_fill(const int* __restrict__ row, const int* __restrict__ col,
                       const float* __restrict__ w,
                       unsigned long long* __restrict__ cursor,
                       unsigned* __restrict__ bkt, int E, int eblocks,
                       const float* __restrict__ W1, const float* __restrict__ W2,
                       unsigned short* __restrict__ W1T, unsigned short* __restrict__ W2T) {
    if ((int)blockIdx.x >= eblocks) {
        const int i = ((int)blockIdx.x - eblocks) * 256 + (int)threadIdx.x;
        if (i < FIN * HDIM) {
            const int k = i >> 7, nn = i & 127;
            W1T[nn * FIN + k] = f2bf(W1[i]);
        } else {
            const int j = i - FIN * HDIM;
            const int nn = j >> 7, k = j & 127;
            W2T[j] = (nn < CDIM) ? f2bf(W2[k * CDIM + nn]) : (unsigned short)0;
        }
        return;
    }
    const int e = blockIdx.x * blockDim.x + threadIdx.x;
    if (e >= E) return;
    const int c = col[e];
    const float we = w[e];
    const unsigned long long wfix = (unsigned long long)(we * 4294967296.0f); // w<1 => <2^32
    const unsigned long long old = atomicAdd(&cursor[c], (1ULL << 40) | wfix);
    const int p = (int)(old >> 40);
    const unsigned wb = (__builtin_bit_cast(unsigned, we) + 0x8000u) >> 16;   // round, 7-bit mant
    if (p < CAP) bkt[(size_t)c * CAP + p] = ((unsigned)row[e] << 15) | (wb & 0x7fffu);
}

// ---------- degree unpack only (weight prep moved into k_fill) ----------
__global__ void k_prep(const unsigned long long* __restrict__ cursor,
                       int* __restrict__ cnt, float* __restrict__ dinv, int n) {
    const int i = blockIdx.x * 256 + threadIdx.x;
    if (i < n) {
        const unsigned long long p = cursor[i];
        cnt[i] = min((int)(p >> 40), CAP);
        const float wsum = (float)(p & ((1ULL << 40) - 1)) * 2.3283064365386963e-10f;
        dinv[i] = rsqrtf(1.0f + wsum);
    }
}

// ---------- GEMM1 (MFMA): h1f8[M,128] (fp8 e4m3) = dinv[m] * (bf16(A) @ W1T^T) ----------
// 64-row blocks (782 total): better CU load-balance than 391x128, LDS 27.6KB.
#define G1_LDA 72   // 64 + 8 pad
__global__ __launch_bounds__(256) void k_gemm1(const float* __restrict__ A,
                                               const unsigned short* __restrict__ W1T,
                                               const float* __restrict__ dinv,
                                               unsigned char* __restrict__ h1f8, int M) {
    __shared__ short As[64 * G1_LDA];
    __shared__ short Bs[128 * G1_LDA];
    const int tid  = threadIdx.x;
    const int wave = tid >> 6;
    const int lane = tid & 63;
    const int quad = lane >> 4;
    const int mr   = lane & 15;
    const int n0w  = wave * 32;            // each wave: all 64 m-rows x 32 n-cols
    const int m0b  = blockIdx.x * 64;

    const int srowA = tid >> 2, spartA = tid & 3;   // A: 64 rows x 4 parts (16 floats)
    const int srowB = tid >> 1, spartB = tid & 1;   // B: 128 rows x 2 parts (32 shorts)

    f32x4 acc[4][2];
#pragma unroll
    for (int i = 0; i < 4; i++)
#pragma unroll
        for (int j = 0; j < 2; j++) acc[i][j] = (f32x4)0.f;

    const int growA = m0b + srowA;
    const bool okA = growA < M;
    const float* ap = A + (size_t)growA * FIN + spartA * 16;
    const unsigned short* bp = W1T + (size_t)srowB * FIN + spartB * 32;

    for (int k0 = 0; k0 < FIN; k0 += 64) {
#pragma unroll
        for (int i = 0; i < 2; i++) {
            float4 v0 = make_float4(0.f, 0.f, 0.f, 0.f), v1 = v0;
            if (okA) {
                v0 = *(const float4*)(ap + k0 + i * 8);
                v1 = *(const float4*)(ap + k0 + i * 8 + 4);
            }
            shortx8 pk;
            pk[0] = (short)f2bf(v0.x); pk[1] = (short)f2bf(v0.y);
            pk[2] = (short)f2bf(v0.z); pk[3] = (short)f2bf(v0.w);
            pk[4] = (short)f2bf(v1.x); pk[5] = (short)f2bf(v1.y);
            pk[6] = (short)f2bf(v1.z); pk[7] = (short)f2bf(v1.w);
            *(shortx8*)&As[srowA * G1_LDA + spartA * 16 + i * 8] = pk;
        }
#pragma unroll
        for (int i = 0; i < 4; i++)
            *(shortx8*)&Bs[srowB * G1_LDA + spartB * 32 + i * 8] =
                *(const shortx8*)(bp + k0 + i * 8);
        __syncthreads();

#pragma unroll
        for (int kk = 0; kk < 2; kk++) {
            shortx8 af[4], bfr[2];
#pragma unroll
            for (int mt = 0; mt < 4; mt++)
                af[mt] = *(shortx8*)&As[(mt * 16 + mr) * G1_LDA + kk * 32 + quad * 8];
#pragma unroll
            for (int nt = 0; nt < 2; nt++)
                bfr[nt] = *(shortx8*)&Bs[(n0w + nt * 16 + mr) * G1_LDA + kk * 32 + quad * 8];
#pragma unroll
            for (int mt = 0; mt < 4; mt++)
#pragma unroll
                for (int nt = 0; nt < 2; nt++)
                    acc[mt][nt] = __builtin_amdgcn_mfma_f32_16x16x32_bf16(
                        af[mt], bfr[nt], acc[mt][nt], 0, 0, 0);
        }
        __syncthreads();
    }
#pragma unroll
    for (int mt = 0; mt < 4; mt++)
#pragma unroll
        for (int r = 0; r < 4; r++) {
            const int om = m0b + mt * 16 + quad * 4 + r;
            if (om < M) {
                const float dv = dinv[om];
#pragma unroll
                for (int nt = 0; nt < 2; nt++)
                    h1f8[(size_t)om * HDIM + n0w + nt * 16 + mr] = f2fp8(dv * acc[mt][nt][r]);
            }
        }
}

// ---------- FUSED gather1 + GEMM2, one wave PER NODE ----------
// Block = 16 nodes, 16 waves (1024 thr). Each wave gathers exactly one node's
// x1 row (identical inner loop to the proven standalone gather1 -> full
// 50000-wave parallelism for the latency-bound random gather), writes 2 bf16
// per lane to LDS. After one barrier, waves 0..2 run the 16x48 MFMA tile
// against L2-resident W2T. x1 never touches global (saves 25.6 MB + a launch).
#define G2_LDA 136   // 128 + 8 pad (shorts)
__global__ __launch_bounds__(1024) void k_g1g2(
    const int* __restrict__ cnt_arr, const unsigned* __restrict__ bkt,
    const unsigned char* __restrict__ h1f8,   // fp8 rows, 128 B pitch
    const float* __restrict__ dinv, const float* __restrict__ b1,
    const unsigned short* __restrict__ W2T,   // [CPAD][HDIM] bf16
    unsigned short* __restrict__ h2a, unsigned short* __restrict__ h2b,
    int n_nodes) {
    __shared__ short Xs[16 * G2_LDA];
    const int tid  = threadIdx.x;
    const int wave = tid >> 6;
    const int lane = tid & 63;
    const int loff = lane * 2;
    const int m0b  = blockIdx.x * 16;
    const int node = m0b + wave;

    unsigned val = 0u;
    if (node < n_nodes) {
        const int cnt = cnt_arr[node];
        const unsigned* base = bkt + (size_t)node * CAP;
        float a0 = 0.f, a1 = 0.f, c0 = 0.f, c1 = 0.f;
        int s = 0;
        for (; s + 8 <= cnt; s += 8) {
            const uint4 qa = *(const uint4*)(base + s);
            const uint4 qb = *(const uint4*)(base + s + 4);
            const unsigned short v0 = *(const unsigned short*)(h1f8 + (size_t)(qa.x >> 15) * HDIM + loff);
            const unsigned short v1 = *(const unsigned short*)(h1f8 + (size_t)(qa.y >> 15) * HDIM + loff);
            const unsigned short v2 = *(const unsigned short*)(h1f8 + (size_t)(qa.z >> 15) * HDIM + loff);
            const unsigned short v3 = *(const unsigned short*)(h1f8 + (size_t)(qa.w >> 15) * HDIM + loff);
            const unsigned short v4 = *(const unsigned short*)(h1f8 + (size_t)(qb.x >> 15) * HDIM + loff);
            const unsigned short v5 = *(const unsigned short*)(h1f8 + (size_t)(qb.y >> 15) * HDIM + loff);
            const unsigned short v6 = *(const unsigned short*)(h1f8 + (size_t)(qb.z >> 15) * HDIM + loff);
            const unsigned short v7 = *(const unsigned short*)(h1f8 + (size_t)(qb.w >> 15) * HDIM + loff);
            const floatx2 f0 = fp8x2_dec(v0), f1 = fp8x2_dec(v1), f2 = fp8x2_dec(v2), f3 = fp8x2_dec(v3);
            const floatx2 f4 = fp8x2_dec(v4), f5 = fp8x2_dec(v5), f6 = fp8x2_dec(v6), f7 = fp8x2_dec(v7);
            a0 += wdec(qa.x) * f0.x + wdec(qa.y) * f1.x + wdec(qa.z) * f2.x + wdec(qa.w) * f3.x;
            a1 += wdec(qa.x) * f0.y + wdec(qa.y) * f1.y + wdec(qa.z) * f2.y + wdec(qa.w) * f3.y;
            c0 += wdec(qb.x) * f4.x + wdec(qb.y) * f5.x + wdec(qb.z) * f6.x + wdec(qb.w) * f7.x;
            c1 += wdec(qb.x) * f4.y + wdec(qb.y) * f5.y + wdec(qb.z) * f6.y + wdec(qb.w) * f7.y;
        }
        for (; s + 4 <= cnt; s += 4) {
            const uint4 qa = *(const uint4*)(base + s);
            const unsigned short v0 = *(const unsigned short*)(h1f8 + (size_t)(qa.x >> 15) * HDIM + loff);
            const unsigned short v1 = *(const unsigned short*)(h1f8 + (size_t)(qa.y >> 15) * HDIM + loff);
            const unsigned short v2 = *(const unsigned short*)(h1f8 + (size_t)(qa.z >> 15) * HDIM + loff);
            const unsigned short v3 = *(const unsigned short*)(h1f8 + (size_t)(qa.w >> 15) * HDIM + loff);
            const floatx2 f0 = fp8x2_dec(v0), f1 = fp8x2_dec(v1), f2 = fp8x2_dec(v2), f3 = fp8x2_dec(v3);
            a0 += wdec(qa.x) * f0.x + wdec(qa.y) * f1.x + wdec(qa.z) * f2.x + wdec(qa.w) * f3.x;
            a1 += wdec(qa.x) * f0.y + wdec(qa.y) * f1.y + wdec(qa.z) * f2.y + wdec(qa.w) * f3.y;
        }
        for (; s < cnt; s++) {
            const unsigned p = base[s];
            const unsigned short v = *(const unsigned short*)(h1f8 + (size_t)(p >> 15) * HDIM + loff);
            const floatx2 f = fp8x2_dec(v);
            a0 += wdec(p) * f.x;
            a1 += wdec(p) * f.y;
        }
        a0 += c0; a1 += c1;
        const float dl = dinv[node];
        const unsigned short vs = *(const unsigned short*)(h1f8 + (size_t)node * HDIM + loff);
        const floatx2 fs = fp8x2_dec(vs);             // self-loop (h1' already dinv-scaled)
        a0 = fmaxf(dl * (a0 + fs.x) + b1[loff], 0.f);
        a1 = fmaxf(dl * (a1 + fs.y) + b1[loff + 1], 0.f);
        val = (unsigned)f2bf(a0) | ((unsigned)f2bf(a1) << 16);
    }
    *(unsigned*)&Xs[wave * G2_LDA + loff] = val;
    __syncthreads();

    // GEMM2 epilogue: waves 0..2 each produce cols [16w, 16w+16) for all 16 rows
    if (wave < 3) {
        const int quad = lane >> 4;
        const int mr   = lane & 15;
        const int nt   = wave;
        f32x4 acc = (f32x4)0.f;
#pragma unroll
        for (int kk = 0; kk < 4; kk++) {
            const shortx8 af  = *(const shortx8*)&Xs[mr * G2_LDA + kk * 32 + quad * 8];
            const shortx8 bfr = *(const shortx8*)(W2T + (size_t)(nt * 16 + mr) * HDIM + kk * 32 + quad * 8);
            acc = __builtin_amdgcn_mfma_f32_16x16x32_bf16(af, bfr, acc, 0, 0, 0);
        }
#pragma unroll
        for (int r = 0; r < 4; r++) {
            const int om = m0b + quad * 4 + r;
            if (om < n_nodes) {
                const float dv = dinv[om];
                if (nt < 2)       h2a[(size_t)om * 32 + nt * 16 + mr] = f2bf(dv * acc[r]);
                else if (mr < 8)  h2b[(size_t)om * 8 + mr] = f2bf(dv * acc[r]);
            }
        }
    }
}

// ---------- gather layer2 + self-loop + bias + log_softmax, wave/node ----------
__global__ __launch_bounds__(256) void k_gather2(
    const int* __restrict__ cnt_arr, const unsigned* __restrict__ bkt,
    const unsigned short* __restrict__ h2a, const unsigned short* __restrict__ h2b,
    const float* __restrict__ dinv, const float* __restrict__ b2,
    float* __restrict__ out, int n_nodes) {
    const int node = blockIdx.x * 4 + (threadIdx.x >> 6);
    const int lane = threadIdx.x & 63;
    if (node >= n_nodes) return;
    const bool act = lane < CDIM;
    const int cnt = cnt_arr[node];
    const unsigned* base = bkt + (size_t)node * CAP;
    // lane -> {array, stride}: cols 0..31 from h2a (stride 32), 32..39 from h2b (stride 8)
    const unsigned short* hb = (lane < 32) ? (h2a + lane) : (h2b + (lane & 7));
    const int hstride = (lane < 32) ? 32 : 8;
    float acc = 0.f, accb = 0.f;
    int s = 0;
    for (; s + 4 <= cnt; s += 4) {
        const uint4 q = *(const uint4*)(base + s);
        if (act) {
            acc  += wdec(q.x) * bfu(hb[(size_t)(q.x >> 15) * hstride])
                  + wdec(q.y) * bfu(hb[(size_t)(q.y >> 15) * hstride]);
            accb += wdec(q.z) * bfu(hb[(size_t)(q.z >> 15) * hstride])
                  + wdec(q.w) * bfu(hb[(size_t)(q.w >> 15) * hstride]);
        }
    }
    for (; s < cnt; s++) {
        const unsigned p = base[s];
        if (act) acc += wdec(p) * bfu(hb[(size_t)(p >> 15) * hstride]);
    }
    acc += accb;
    if (act) {
        const float dl = dinv[node];
        acc = dl * (acc + bfu(hb[(size_t)node * hstride])) + b2[lane];
    }
    float m = act ? acc : -INFINITY;
#pragma unroll
    for (int off = 32; off; off >>= 1) m = fmaxf(m, __shfl_xor(m, off));
    float se = act ? expf(acc - m) : 0.f;
#pragma unroll
    for (int off = 32; off; off >>= 1) se += __shfl_xor(se, off);
    if (act) out[(size_t)node * CDIM + lane] = acc - m - logf(se);
}

extern "C" void kernel_launch(void* const* d_in, const int* in_sizes, int n_in,
                              void* d_out, int out_size, void* d_ws, size_t ws_size,
                              hipStream_t stream) {
    const float* features = (const float*)d_in[0];
    const int*   eidx     = (const int*)d_in[1];
    const float* ew       = (const float*)d_in[2];
    const float* W1       = (const float*)d_in[3];
    const float* b1       = (const float*)d_in[4];
    const float* W2       = (const float*)d_in[5];
    const float* b2       = (const float*)d_in[6];
    float* out = (float*)d_out;

    const int Nn = in_sizes[0] / FIN;   // 50000
    const int E  = in_sizes[2];         // 800000
    const int* row = eidx;
    const int* col = eidx + E;

    char* ws = (char*)d_ws;
    size_t off = 0;
    auto alloc = [&](size_t bytes) { void* p = ws + off; off += (bytes + 255) & ~(size_t)255; return p; };
    unsigned long long* cursor = (unsigned long long*)alloc((size_t)Nn * 8);
    int*      cnt          = (int*)     alloc((size_t)Nn * 4);
    float*    dinv         = (float*)   alloc((size_t)Nn * 4);
    unsigned* bkt          = (unsigned*)alloc((size_t)Nn * CAP * 4);
    unsigned short* W1T    = (unsigned short*)alloc((size_t)FIN * HDIM * 2);
    unsigned short* W2T    = (unsigned short*)alloc((size_t)CPAD * HDIM * 2);
    unsigned char*  h1f8   = (unsigned char*) alloc((size_t)Nn * HDIM);
    unsigned short* h2a    = (unsigned short*)alloc((size_t)Nn * 32 * 2);
    unsigned short* h2b    = (unsigned short*)alloc((size_t)Nn * 8 * 2);

    const int eblocks = (E + 255) / 256;

    // bucket build (packed 64-bit atomic per edge) + weight transpose in one launch
    hipMemsetAsync(cursor, 0, (size_t)Nn * 8, stream);
    k_fill<<<eblocks + PREPB, 256, 0, stream>>>(row, col, ew, cursor, bkt, E, eblocks,
                                                W1, W2, W1T, W2T);
    // degree unpack
    k_prep<<<(Nn + 255) / 256, 256, 0, stream>>>(cursor, cnt, dinv, Nn);
    // layer 1 transform
    k_gemm1<<<(Nn + 63) / 64, 256, 0, stream>>>(features, W1T, dinv, h1f8, Nn);
    // fused layer-1 aggregate + layer-2 transform (x1 stays in LDS, 1 wave/node)
    k_g1g2<<<(Nn + 15) / 16, 1024, 0, stream>>>(cnt, bkt, h1f8, dinv, b1, W2T,
                                                h2a, h2b, Nn);
    // layer-2 aggregate + log_softmax
    k_gather2<<<(Nn + 3) / 4, 256, 0, stream>>>(cnt, bkt, h2a, h2b, dinv, b2, out, Nn);
}